// Round 1
// baseline (354.838 us; speedup 1.0000x reference)
//
#include <hip/hip_runtime.h>
#include <stdint.h>

// Problem: B=4, S=2048, D=1024, H=16, HD=64. All inputs fp32.
// Pipeline: convert->bf16; Q,K = x@w^T+b in [B,H,S,HD]; V^T in [B,H,HD,S]
// (swapped-operand MFMA GEMM); flash attention -> ao [B,S,D] bf16; out = ao@wo^T+bo fp32.
// Workspace layout (needs >= 72 MB):
//   [0,16M)   xb (bf16 x)  -- reused as ao after QKV gemms
//   [16M..24M) wqb,wkb,wvb,wob (2MB each)
//   [24M,40M) q   [40M,56M) k   [56M,72M) vt

#define B_ 4
#define S_ 2048
#define D_ 1024
#define H_ 16
#define HD_ 64
#define M_ (B_ * S_)

typedef __bf16 bf16x8 __attribute__((ext_vector_type(8)));
typedef float f32x4 __attribute__((ext_vector_type(4)));
typedef unsigned short u16;

__device__ __forceinline__ u16 f2bf(float f) {
  union { float f; unsigned u; } v; v.f = f;
  unsigned u = v.u;
  u += 0x7fff + ((u >> 16) & 1);   // round-to-nearest-even
  return (u16)(u >> 16);
}

__device__ __forceinline__ void gl2lds16(const void* g, void* l) {
  __builtin_amdgcn_global_load_lds(
      (const __attribute__((address_space(1))) unsigned int*)g,
      (__attribute__((address_space(3))) unsigned int*)l, 16, 0, 0);
}

// ---------------- convert fp32 -> bf16 (x and 4 weights) ----------------
__global__ __launch_bounds__(256) void convert_kernel(
    const float* __restrict__ x, const float* __restrict__ wq,
    const float* __restrict__ wk, const float* __restrict__ wv,
    const float* __restrict__ wo, u16* __restrict__ xb, u16* __restrict__ wqb,
    u16* __restrict__ wkb, u16* __restrict__ wvb, u16* __restrict__ wob) {
  const int64_t NX = (int64_t)M_ * D_ / 4;  // 2M float4
  const int64_t NW = (int64_t)D_ * D_ / 4;  // 256K float4
  int64_t i = (int64_t)blockIdx.x * blockDim.x + threadIdx.x;
  const float* src; u16* dst; int64_t off;
  if (i < NX)              { src = x;  dst = xb;  off = i; }
  else if (i < NX + NW)    { src = wq; dst = wqb; off = i - NX; }
  else if (i < NX + 2*NW)  { src = wk; dst = wkb; off = i - NX - NW; }
  else if (i < NX + 3*NW)  { src = wv; dst = wvb; off = i - NX - 2*NW; }
  else                     { src = wo; dst = wob; off = i - NX - 3*NW; }
  float4 v = reinterpret_cast<const float4*>(src)[off];
  ushort4 o;
  o.x = f2bf(v.x); o.y = f2bf(v.y); o.z = f2bf(v.z); o.w = f2bf(v.w);
  reinterpret_cast<ushort4*>(dst)[off] = o;
}

// ---------------- bf16 MFMA GEMM: C = A(MxK) @ Bw(NxK)^T + bias ----------------
// 128x128 tile, BK=64, 4 waves (each 64x64 = 4x4 16x16 frags).
// LDS XOR-swizzle: 16B chunk slot = chunk ^ (row&7); staged via global_load_lds
// with pre-swizzled per-lane global source (swizzle both sides, guide rule 21).
// MODE 0: bf16 out -> [B,H,S,HD]  (Q, K projections)
// MODE 1: swapped operands, bf16 out -> [B,H,HD,S]  (V^T)
// MODE 2: fp32 out -> [M,N] row-major (final projection into d_out)
template <int MODE>
__global__ __launch_bounds__(256) void gemm_kernel(
    const u16* __restrict__ A, const u16* __restrict__ Bw,
    const float* __restrict__ bias, void* __restrict__ out) {
  __shared__ u16 As[128 * 64];
  __shared__ u16 Bs[128 * 64];
  const int tid = threadIdx.x;
  const int lane = tid & 63;
  const int wid = tid >> 6;
  const int row0 = blockIdx.y * 128;  // M
  const int col0 = blockIdx.x * 128;  // N
  const int K = D_;
  const int wr = (wid >> 1) * 64;
  const int wc = (wid & 1) * 64;

  f32x4 acc[4][4] = {};
  const int srow = lane >> 3;          // 0..7 row within 8-row group
  const int cc = (lane & 7) ^ srow;    // global chunk to fetch (inverse swizzle)

  for (int kt = 0; kt < K; kt += 64) {
    __syncthreads();
    for (int t = 0; t < 4; ++t) {
      int r = (wid * 4 + t) * 8 + srow;
      gl2lds16(A + (int64_t)(row0 + r) * K + kt + cc * 8,
               (char*)As + (wid * 4 + t) * 1024);
      gl2lds16(Bw + (int64_t)(col0 + r) * K + kt + cc * 8,
               (char*)Bs + (wid * 4 + t) * 1024);
    }
    __syncthreads();

    bf16x8 af[4][2], bfr[4][2];
#pragma unroll
    for (int mi = 0; mi < 4; ++mi)
#pragma unroll
      for (int ks = 0; ks < 2; ++ks) {
        int c = ks * 4 + (lane >> 4);
        int ra = wr + mi * 16 + (lane & 15);
        af[mi][ks] = *reinterpret_cast<const bf16x8*>(
            (char*)As + ra * 128 + ((c ^ (ra & 7)) << 4));
        int rb = wc + mi * 16 + (lane & 15);
        bfr[mi][ks] = *reinterpret_cast<const bf16x8*>(
            (char*)Bs + rb * 128 + ((c ^ (rb & 7)) << 4));
      }
#pragma unroll
    for (int ks = 0; ks < 2; ++ks)
#pragma unroll
      for (int mi = 0; mi < 4; ++mi)
#pragma unroll
        for (int ni = 0; ni < 4; ++ni) {
          if (MODE == 1)
            acc[mi][ni] = __builtin_amdgcn_mfma_f32_16x16x32_bf16(
                bfr[ni][ks], af[mi][ks], acc[mi][ni], 0, 0, 0);
          else
            acc[mi][ni] = __builtin_amdgcn_mfma_f32_16x16x32_bf16(
                af[mi][ks], bfr[ni][ks], acc[mi][ni], 0, 0, 0);
        }
  }

  if (MODE == 0) {
    u16* o = (u16*)out;
#pragma unroll
    for (int mi = 0; mi < 4; ++mi)
#pragma unroll
      for (int ni = 0; ni < 4; ++ni) {
        int j = col0 + wc + ni * 16 + (lane & 15);
        float bv = bias[j];
        int h = j >> 6, hd = j & 63;
#pragma unroll
        for (int r = 0; r < 4; ++r) {
          int i = row0 + wr + mi * 16 + (lane >> 4) * 4 + r;
          int b = i >> 11, s = i & 2047;
          o[((int64_t)(b * H_ + h) * S_ + s) * HD_ + hd] = f2bf(acc[mi][ni][r] + bv);
        }
      }
  } else if (MODE == 1) {
    u16* o = (u16*)out;
#pragma unroll
    for (int mi = 0; mi < 4; ++mi)
#pragma unroll
      for (int ni = 0; ni < 4; ++ni) {
        int i = row0 + wr + mi * 16 + (lane & 15);  // x row
        int b = i >> 11, s = i & 2047;
#pragma unroll
        for (int r = 0; r < 4; ++r) {
          int j = col0 + wc + ni * 16 + (lane >> 4) * 4 + r;  // v output col
          int h = j >> 6, hd = j & 63;
          o[((int64_t)(b * H_ + h) * HD_ + hd) * S_ + s] = f2bf(acc[mi][ni][r] + bias[j]);
        }
      }
  } else {
    float* o = (float*)out;
#pragma unroll
    for (int mi = 0; mi < 4; ++mi)
#pragma unroll
      for (int ni = 0; ni < 4; ++ni) {
        int j = col0 + wc + ni * 16 + (lane & 15);
        float bv = bias[j];
#pragma unroll
        for (int r = 0; r < 4; ++r) {
          int i = row0 + wr + mi * 16 + (lane >> 4) * 4 + r;
          o[(int64_t)i * D_ + j] = acc[mi][ni][r] + bv;
        }
      }
  }
}

// ---------------- flash attention ----------------
// grid (S/128, B*H), 4 waves; wave owns 32 q-rows. KV tiles of 64.
// Q [B,H,S,HD], K [B,H,S,HD], Vt [B,H,HD,S] all bf16; out ao [B,S,D] bf16.
__global__ __launch_bounds__(256) void attn_kernel(
    const u16* __restrict__ Q, const u16* __restrict__ Kg,
    const u16* __restrict__ Vt, u16* __restrict__ AO) {
  __shared__ u16 Ks[64 * 64];      // swizzled [kv][hd]
  __shared__ u16 Vs[64 * 64];      // swizzled [hd][kv]
  __shared__ u16 Ps[4][32 * 64];   // per-wave swizzled [q][kv]
  const int tid = threadIdx.x;
  const int lane = tid & 63;
  const int wid = tid >> 6;
  const int bh = blockIdx.y;
  const int qw = blockIdx.x * 128 + wid * 32;

  bf16x8 qf[2][2];
#pragma unroll
  for (int mi = 0; mi < 2; ++mi)
#pragma unroll
    for (int ks = 0; ks < 2; ++ks) {
      int qr = qw + mi * 16 + (lane & 15);
      qf[mi][ks] = *reinterpret_cast<const bf16x8*>(
          Q + ((int64_t)bh * S_ + qr) * HD_ + ks * 32 + (lane >> 4) * 8);
    }

  f32x4 oacc[2][4] = {};
  float mrow[8], lrow[8];
#pragma unroll
  for (int t = 0; t < 8; ++t) { mrow[t] = -1e30f; lrow[t] = 0.f; }

  const int srow = lane >> 3;
  const int cc = (lane & 7) ^ srow;
  u16* pw = Ps[wid];

  for (int kv0 = 0; kv0 < S_; kv0 += 64) {
    __syncthreads();
    for (int t = 0; t < 2; ++t) {
      int r = (wid * 2 + t) * 8 + srow;
      gl2lds16(Kg + ((int64_t)bh * S_ + kv0 + r) * HD_ + cc * 8,
               (char*)Ks + (wid * 2 + t) * 1024);
      gl2lds16(Vt + ((int64_t)bh * HD_ + r) * S_ + kv0 + cc * 8,
               (char*)Vs + (wid * 2 + t) * 1024);
    }
    __syncthreads();

    // QK^T -> scores [32q][64kv] per wave
    f32x4 sc[2][4] = {};
    bf16x8 kf[4][2];
#pragma unroll
    for (int ni = 0; ni < 4; ++ni)
#pragma unroll
      for (int ks = 0; ks < 2; ++ks) {
        int r = ni * 16 + (lane & 15);
        int c = ks * 4 + (lane >> 4);
        kf[ni][ks] = *reinterpret_cast<const bf16x8*>(
            (char*)Ks + r * 128 + ((c ^ (r & 7)) << 4));
      }
#pragma unroll
    for (int ks = 0; ks < 2; ++ks)
#pragma unroll
      for (int mi = 0; mi < 2; ++mi)
#pragma unroll
        for (int ni = 0; ni < 4; ++ni)
          sc[mi][ni] = __builtin_amdgcn_mfma_f32_16x16x32_bf16(
              qf[mi][ks], kf[ni][ks], sc[mi][ni], 0, 0, 0);

    // online softmax; lane holds rows q_local = mi*16+(lane>>4)*4+r, col ni*16+(lane&15)
    float alpha[8];
#pragma unroll
    for (int mi = 0; mi < 2; ++mi)
#pragma unroll
      for (int r = 0; r < 4; ++r) {
        int t8 = mi * 4 + r;
        float mx = -1e30f;
#pragma unroll
        for (int ni = 0; ni < 4; ++ni) {
          sc[mi][ni][r] *= 0.125f;  // 1/sqrt(64), exact
          mx = fmaxf(mx, sc[mi][ni][r]);
        }
        for (int d = 1; d < 16; d <<= 1) mx = fmaxf(mx, __shfl_xor(mx, d));
        float mnew = fmaxf(mrow[t8], mx);
        float a = __expf(mrow[t8] - mnew);
        float rsum = 0.f;
#pragma unroll
        for (int ni = 0; ni < 4; ++ni) {
          float p = __expf(sc[mi][ni][r] - mnew);
          sc[mi][ni][r] = p;
          rsum += p;
        }
        for (int d = 1; d < 16; d <<= 1) rsum += __shfl_xor(rsum, d);
        mrow[t8] = mnew;
        lrow[t8] = lrow[t8] * a + rsum;
        alpha[t8] = a;
      }
#pragma unroll
    for (int mi = 0; mi < 2; ++mi)
#pragma unroll
      for (int ni = 0; ni < 4; ++ni)
#pragma unroll
        for (int r = 0; r < 4; ++r) oacc[mi][ni][r] *= alpha[mi * 4 + r];

    // P -> per-wave LDS (bf16, swizzled)
#pragma unroll
    for (int mi = 0; mi < 2; ++mi)
#pragma unroll
      for (int ni = 0; ni < 4; ++ni)
#pragma unroll
        for (int r = 0; r < 4; ++r) {
          int qr = mi * 16 + (lane >> 4) * 4 + r;
          int kc = ni * 16 + (lane & 15);
          int byte = qr * 128 + (((kc >> 3) ^ (qr & 7)) << 4) + (kc & 7) * 2;
          *(u16*)((char*)pw + byte) = f2bf(sc[mi][ni][r]);
        }
    __syncthreads();

    // PV: out[q][hd] += P[q][kv] * Vt[hd][kv]
    bf16x8 pf[2][2], vf[4][2];
#pragma unroll
    for (int mi = 0; mi < 2; ++mi)
#pragma unroll
      for (int ks = 0; ks < 2; ++ks) {
        int r = mi * 16 + (lane & 15);
        int c = ks * 4 + (lane >> 4);
        pf[mi][ks] = *reinterpret_cast<const bf16x8*>(
            (char*)pw + r * 128 + ((c ^ (r & 7)) << 4));
      }
#pragma unroll
    for (int ni = 0; ni < 4; ++ni)
#pragma unroll
      for (int ks = 0; ks < 2; ++ks) {
        int r = ni * 16 + (lane & 15);
        int c = ks * 4 + (lane >> 4);
        vf[ni][ks] = *reinterpret_cast<const bf16x8*>(
            (char*)Vs + r * 128 + ((c ^ (r & 7)) << 4));
      }
#pragma unroll
    for (int ks = 0; ks < 2; ++ks)
#pragma unroll
      for (int mi = 0; mi < 2; ++mi)
#pragma unroll
        for (int ni = 0; ni < 4; ++ni)
          oacc[mi][ni] = __builtin_amdgcn_mfma_f32_16x16x32_bf16(
              pf[mi][ks], vf[ni][ks], oacc[mi][ni], 0, 0, 0);
  }

  const int b = bh >> 4, h = bh & 15;
#pragma unroll
  for (int mi = 0; mi < 2; ++mi)
#pragma unroll
    for (int ni = 0; ni < 4; ++ni)
#pragma unroll
      for (int r = 0; r < 4; ++r) {
        int qr = qw + mi * 16 + (lane >> 4) * 4 + r;
        int hd = ni * 16 + (lane & 15);
        float v = oacc[mi][ni][r] / lrow[mi * 4 + r];
        AO[((int64_t)(b * S_ + qr)) * D_ + h * HD_ + hd] = f2bf(v);
      }
}

extern "C" void kernel_launch(void* const* d_in, const int* in_sizes, int n_in,
                              void* d_out, int out_size, void* d_ws, size_t ws_size,
                              hipStream_t stream) {
  const float* x  = (const float*)d_in[0];
  const float* wq = (const float*)d_in[1];
  const float* bq = (const float*)d_in[2];
  const float* wk = (const float*)d_in[3];
  const float* bk = (const float*)d_in[4];
  const float* wv = (const float*)d_in[5];
  const float* bv = (const float*)d_in[6];
  const float* wo = (const float*)d_in[7];
  const float* bo = (const float*)d_in[8];
  char* ws = (char*)d_ws;
  u16* xb  = (u16*)ws;                        // 16MB
  u16* wqb = (u16*)(ws + (16ll << 20));
  u16* wkb = (u16*)(ws + (18ll << 20));
  u16* wvb = (u16*)(ws + (20ll << 20));
  u16* wob = (u16*)(ws + (22ll << 20));
  u16* q   = (u16*)(ws + (24ll << 20));       // [B,H,S,HD]
  u16* k   = (u16*)(ws + (40ll << 20));       // [B,H,S,HD]
  u16* vt  = (u16*)(ws + (56ll << 20));       // [B,H,HD,S]
  u16* ao  = xb;                              // reuse xb after QKV gemms

  convert_kernel<<<12288, 256, 0, stream>>>(x, wq, wk, wv, wo, xb, wqb, wkb, wvb, wob);
  dim3 gg(D_ / 128, M_ / 128);  // (8, 64)
  gemm_kernel<0><<<gg, 256, 0, stream>>>(xb, wqb, bq, q);
  gemm_kernel<0><<<gg, 256, 0, stream>>>(xb, wkb, bk, k);
  gemm_kernel<1><<<gg, 256, 0, stream>>>(xb, wvb, bv, vt);
  attn_kernel<<<dim3(S_ / 128, B_ * H_), 256, 0, stream>>>(q, k, vt, ao);
  gemm_kernel<2><<<gg, 256, 0, stream>>>(ao, wob, bo, d_out);
}

// Round 3
// 251.788 us; speedup vs baseline: 1.4093x; 1.4093x over previous
//
#include <hip/hip_runtime.h>
#include <stdint.h>

// B=4, S=2048, D=1024, H=16, HD=64. All inputs fp32.
// convert->bf16; Q(pre-scaled by 0.125*log2e),K in [B,H,S,HD]; V^T [B,H,HD,S];
// flash attention (swapped QK^T, in-lane softmax, defer-max, dbuf K/V) -> ao bf16;
// out = ao@wo^T+bo fp32.

#define B_ 4
#define S_ 2048
#define D_ 1024
#define H_ 16
#define HD_ 64
#define M_ (B_ * S_)

typedef __bf16 bf16x8 __attribute__((ext_vector_type(8)));
typedef __bf16 bf16x4 __attribute__((ext_vector_type(4)));
typedef float f32x4 __attribute__((ext_vector_type(4)));
typedef unsigned short u16;

// 0.125 (1/sqrt(HD)) * log2(e): scores come out in log2 units
#define QSCALE 0.18033688011112042f
#define THR2 11.0f  // defer-max threshold in log2 units (~e^7.6)

__device__ __forceinline__ u16 f2bf(float f) {
  union { float f; unsigned u; } v; v.f = f;
  unsigned u = v.u;
  u += 0x7fff + ((u >> 16) & 1);
  return (u16)(u >> 16);
}

__device__ __forceinline__ float exp2_fast(float x) {
#if __has_builtin(__builtin_amdgcn_exp2f)
  return __builtin_amdgcn_exp2f(x);
#else
  return __expf(x * 0.69314718056f);
#endif
}

__device__ __forceinline__ void gl2lds16(const void* g, void* l) {
  __builtin_amdgcn_global_load_lds(
      (const __attribute__((address_space(1))) unsigned int*)g,
      (__attribute__((address_space(3))) unsigned int*)l, 16, 0, 0);
}

// ---------------- convert fp32 -> bf16 ----------------
__global__ __launch_bounds__(256) void convert_kernel(
    const float* __restrict__ x, const float* __restrict__ wq,
    const float* __restrict__ wk, const float* __restrict__ wv,
    const float* __restrict__ wo, u16* __restrict__ xb, u16* __restrict__ wqb,
    u16* __restrict__ wkb, u16* __restrict__ wvb, u16* __restrict__ wob) {
  const int64_t NX = (int64_t)M_ * D_ / 4;
  const int64_t NW = (int64_t)D_ * D_ / 4;
  int64_t i = (int64_t)blockIdx.x * blockDim.x + threadIdx.x;
  const float* src; u16* dst; int64_t off;
  if (i < NX)              { src = x;  dst = xb;  off = i; }
  else if (i < NX + NW)    { src = wq; dst = wqb; off = i - NX; }
  else if (i < NX + 2*NW)  { src = wk; dst = wkb; off = i - NX - NW; }
  else if (i < NX + 3*NW)  { src = wv; dst = wvb; off = i - NX - 2*NW; }
  else                     { src = wo; dst = wob; off = i - NX - 3*NW; }
  float4 v = reinterpret_cast<const float4*>(src)[off];
  ushort4 o;
  o.x = f2bf(v.x); o.y = f2bf(v.y); o.z = f2bf(v.z); o.w = f2bf(v.w);
  reinterpret_cast<ushort4*>(dst)[off] = o;
}

// ---------------- bf16 MFMA GEMM: C = A(MxK) @ Bw(NxK)^T + bias ----------------
// MODE 0: bf16 out [B,H,S,HD] (K proj)   MODE 3: same, scaled by QSCALE (Q proj)
// MODE 1: swapped, bf16 out [B,H,HD,S] (V^T)   MODE 2: fp32 out [M,N] (final)
template <int MODE>
__global__ __launch_bounds__(256) void gemm_kernel(
    const u16* __restrict__ A, const u16* __restrict__ Bw,
    const float* __restrict__ bias, void* __restrict__ out) {
  __shared__ u16 As[128 * 64];
  __shared__ u16 Bs[128 * 64];
  const int tid = threadIdx.x;
  const int lane = tid & 63;
  const int wid = tid >> 6;
  const int row0 = blockIdx.y * 128;
  const int col0 = blockIdx.x * 128;
  const int K = D_;
  const int wr = (wid >> 1) * 64;
  const int wc = (wid & 1) * 64;

  f32x4 acc[4][4] = {};
  const int srow = lane >> 3;
  const int cc = (lane & 7) ^ srow;

  for (int kt = 0; kt < K; kt += 64) {
    __syncthreads();
    for (int t = 0; t < 4; ++t) {
      int r = (wid * 4 + t) * 8 + srow;
      gl2lds16(A + (int64_t)(row0 + r) * K + kt + cc * 8,
               (char*)As + (wid * 4 + t) * 1024);
      gl2lds16(Bw + (int64_t)(col0 + r) * K + kt + cc * 8,
               (char*)Bs + (wid * 4 + t) * 1024);
    }
    __syncthreads();

    bf16x8 af[4][2], bfr[4][2];
#pragma unroll
    for (int mi = 0; mi < 4; ++mi)
#pragma unroll
      for (int ks = 0; ks < 2; ++ks) {
        int c = ks * 4 + (lane >> 4);
        int ra = wr + mi * 16 + (lane & 15);
        af[mi][ks] = *reinterpret_cast<const bf16x8*>(
            (char*)As + ra * 128 + ((c ^ (ra & 7)) << 4));
        int rb = wc + mi * 16 + (lane & 15);
        bfr[mi][ks] = *reinterpret_cast<const bf16x8*>(
            (char*)Bs + rb * 128 + ((c ^ (rb & 7)) << 4));
      }
#pragma unroll
    for (int ks = 0; ks < 2; ++ks)
#pragma unroll
      for (int mi = 0; mi < 4; ++mi)
#pragma unroll
        for (int ni = 0; ni < 4; ++ni) {
          if (MODE == 1)
            acc[mi][ni] = __builtin_amdgcn_mfma_f32_16x16x32_bf16(
                bfr[ni][ks], af[mi][ks], acc[mi][ni], 0, 0, 0);
          else
            acc[mi][ni] = __builtin_amdgcn_mfma_f32_16x16x32_bf16(
                af[mi][ks], bfr[ni][ks], acc[mi][ni], 0, 0, 0);
        }
  }

  if (MODE == 0 || MODE == 3) {
    u16* o = (u16*)out;
#pragma unroll
    for (int mi = 0; mi < 4; ++mi)
#pragma unroll
      for (int ni = 0; ni < 4; ++ni) {
        int j = col0 + wc + ni * 16 + (lane & 15);
        float bv = bias[j];
        int h = j >> 6, hd = j & 63;
#pragma unroll
        for (int r = 0; r < 4; ++r) {
          int i = row0 + wr + mi * 16 + (lane >> 4) * 4 + r;
          int b = i >> 11, s = i & 2047;
          float val = acc[mi][ni][r] + bv;
          if (MODE == 3) val *= QSCALE;
          o[((int64_t)(b * H_ + h) * S_ + s) * HD_ + hd] = f2bf(val);
        }
      }
  } else if (MODE == 1) {
    u16* o = (u16*)out;
#pragma unroll
    for (int mi = 0; mi < 4; ++mi)
#pragma unroll
      for (int ni = 0; ni < 4; ++ni) {
        int i = row0 + wr + mi * 16 + (lane & 15);
        int b = i >> 11, s = i & 2047;
#pragma unroll
        for (int r = 0; r < 4; ++r) {
          int j = col0 + wc + ni * 16 + (lane >> 4) * 4 + r;
          int h = j >> 6, hd = j & 63;
          o[((int64_t)(b * H_ + h) * HD_ + hd) * S_ + s] = f2bf(acc[mi][ni][r] + bias[j]);
        }
      }
  } else {
    float* o = (float*)out;
#pragma unroll
    for (int mi = 0; mi < 4; ++mi)
#pragma unroll
      for (int ni = 0; ni < 4; ++ni) {
        int j = col0 + wc + ni * 16 + (lane & 15);
        float bv = bias[j];
#pragma unroll
        for (int r = 0; r < 4; ++r) {
          int i = row0 + wr + mi * 16 + (lane >> 4) * 4 + r;
          o[(int64_t)i * D_ + j] = acc[mi][ni][r] + bv;
        }
      }
  }
}

// ---------------- flash attention (swapped QK^T, in-lane softmax) ----------------
// grid (S/128, B*H), 4 waves; wave owns 32 q-rows. KV tiles of 64, double-buffered.
// Q pre-scaled by 0.125*log2e; softmax in log2 units via exp2.
__global__ __launch_bounds__(256) void attn_kernel(
    const u16* __restrict__ Q, const u16* __restrict__ Kg,
    const u16* __restrict__ Vt, u16* __restrict__ AO) {
  __shared__ u16 Ks[2][64 * 64];   // swizzled [kv][hd]
  __shared__ u16 Vs[2][64 * 64];   // swizzled [hd][kv]
  __shared__ u16 Ps[4][32 * 64];   // per-wave swizzled [q][kv]
  const int tid = threadIdx.x;
  const int lane = tid & 63;
  const int g = lane >> 4;         // 4-lane-group id (kv-quarter)
  const int wid = tid >> 6;
  const int bh = blockIdx.y;
  const int qw = blockIdx.x * 128 + wid * 32;

  // Q as B-operand fragments: col(q)=lane&15, k = ks*32 + g*8 + j
  bf16x8 qf[2][2];
#pragma unroll
  for (int mi = 0; mi < 2; ++mi)
#pragma unroll
    for (int ks = 0; ks < 2; ++ks) {
      int qr = qw + mi * 16 + (lane & 15);
      qf[mi][ks] = *reinterpret_cast<const bf16x8*>(
          Q + ((int64_t)bh * S_ + qr) * HD_ + ks * 32 + g * 8);
    }

  f32x4 oacc[2][4] = {};
  float mrow[2] = {-1e30f, -1e30f};
  float lrow[2] = {0.f, 0.f};

  const int srow = lane >> 3;
  const int cc = (lane & 7) ^ srow;
  char* pw = (char*)Ps[wid];

  // prologue: stage tile 0 -> buf 0
#pragma unroll
  for (int tt = 0; tt < 2; ++tt) {
    int r = (wid * 2 + tt) * 8 + srow;
    gl2lds16(Kg + ((int64_t)bh * S_ + r) * HD_ + cc * 8,
             (char*)Ks[0] + (wid * 2 + tt) * 1024);
    gl2lds16(Vt + ((int64_t)bh * HD_ + r) * S_ + cc * 8,
             (char*)Vs[0] + (wid * 2 + tt) * 1024);
  }

  const int NT = S_ / 64;
  for (int t = 0; t < NT; ++t) {
    const int cur = t & 1;
    // tile t's 4 loads are the only outstanding vmem; drain, then sync all waves
    asm volatile("s_waitcnt vmcnt(0)" ::: "memory");
    __builtin_amdgcn_s_barrier();
    // prefetch tile t+1 into buf^1 (flies under this tile's compute)
    if (t + 1 < NT) {
      int kv0 = (t + 1) * 64;
#pragma unroll
      for (int tt = 0; tt < 2; ++tt) {
        int r = (wid * 2 + tt) * 8 + srow;
        gl2lds16(Kg + ((int64_t)bh * S_ + kv0 + r) * HD_ + cc * 8,
                 (char*)Ks[cur ^ 1] + (wid * 2 + tt) * 1024);
        gl2lds16(Vt + ((int64_t)bh * HD_ + r) * S_ + kv0 + cc * 8,
                 (char*)Vs[cur ^ 1] + (wid * 2 + tt) * 1024);
      }
    }

    // QK^T swapped: sc[mi][ni] = mfma(K_frag ni, Q_frag mi) -> C[kv][q]
    // lane holds, per mi (q = mi*16 + lane&15), kv = ni*16 + g*4 + r
    f32x4 sc[2][4] = {};
    {
      bf16x8 kf[4][2];
#pragma unroll
      for (int ni = 0; ni < 4; ++ni)
#pragma unroll
        for (int ks = 0; ks < 2; ++ks) {
          int r = ni * 16 + (lane & 15);
          int c = ks * 4 + g;
          kf[ni][ks] = *reinterpret_cast<const bf16x8*>(
              (const char*)Ks[cur] + r * 128 + ((c ^ (lane & 7)) << 4));
        }
      __builtin_amdgcn_s_setprio(1);
#pragma unroll
      for (int ks = 0; ks < 2; ++ks)
#pragma unroll
        for (int mi = 0; mi < 2; ++mi)
#pragma unroll
          for (int ni = 0; ni < 4; ++ni)
            sc[mi][ni] = __builtin_amdgcn_mfma_f32_16x16x32_bf16(
                kf[ni][ks], qf[mi][ks], sc[mi][ni], 0, 0, 0);
      __builtin_amdgcn_s_setprio(0);
    }

    // row max (in-lane tree + 2 shfl), defer-max check
    float mx[2];
    int ok = 1;
#pragma unroll
    for (int mi = 0; mi < 2; ++mi) {
      float a0 = fmaxf(fmaxf(sc[mi][0][0], sc[mi][0][1]), fmaxf(sc[mi][0][2], sc[mi][0][3]));
      float a1 = fmaxf(fmaxf(sc[mi][1][0], sc[mi][1][1]), fmaxf(sc[mi][1][2], sc[mi][1][3]));
      float a2 = fmaxf(fmaxf(sc[mi][2][0], sc[mi][2][1]), fmaxf(sc[mi][2][2], sc[mi][2][3]));
      float a3 = fmaxf(fmaxf(sc[mi][3][0], sc[mi][3][1]), fmaxf(sc[mi][3][2], sc[mi][3][3]));
      float m0 = fmaxf(fmaxf(a0, a1), fmaxf(a2, a3));
      m0 = fmaxf(m0, __shfl_xor(m0, 16));
      m0 = fmaxf(m0, __shfl_xor(m0, 32));
      mx[mi] = m0;
      ok &= (m0 - mrow[mi] <= THR2) ? 1 : 0;
    }
    if (!__all(ok)) {  // rare rescale path
      float alpha[2];
#pragma unroll
      for (int mi = 0; mi < 2; ++mi) {
        float mnew = fmaxf(mrow[mi], mx[mi]);
        alpha[mi] = exp2_fast(mrow[mi] - mnew);
        mrow[mi] = mnew;
        lrow[mi] *= alpha[mi];
      }
#pragma unroll
      for (int mi2 = 0; mi2 < 2; ++mi2)
#pragma unroll
        for (int r = 0; r < 4; ++r) {
          float a = __shfl(alpha[mi2], (g << 2) | r);
#pragma unroll
          for (int ni = 0; ni < 4; ++ni) oacc[mi2][ni][r] *= a;
        }
    }
    // p = exp2(s - m), row sum, P -> per-wave LDS (packed b64)
#pragma unroll
    for (int mi = 0; mi < 2; ++mi) {
      float m = mrow[mi];
      float s0 = 0.f, s1 = 0.f, s2 = 0.f, s3 = 0.f;
#pragma unroll
      for (int ni = 0; ni < 4; ++ni) {
        float p0 = exp2_fast(sc[mi][ni][0] - m);
        float p1 = exp2_fast(sc[mi][ni][1] - m);
        float p2 = exp2_fast(sc[mi][ni][2] - m);
        float p3 = exp2_fast(sc[mi][ni][3] - m);
        sc[mi][ni][0] = p0; sc[mi][ni][1] = p1;
        sc[mi][ni][2] = p2; sc[mi][ni][3] = p3;
        if (ni == 0) s0 = (p0 + p1) + (p2 + p3);
        else if (ni == 1) s1 = (p0 + p1) + (p2 + p3);
        else if (ni == 2) s2 = (p0 + p1) + (p2 + p3);
        else s3 = (p0 + p1) + (p2 + p3);
      }
      float rs = (s0 + s1) + (s2 + s3);
      rs += __shfl_xor(rs, 16);
      rs += __shfl_xor(rs, 32);
      lrow[mi] += rs;
      int q = mi * 16 + (lane & 15);
#pragma unroll
      for (int ni = 0; ni < 4; ++ni) {
        bf16x4 pk;
        pk[0] = (__bf16)sc[mi][ni][0]; pk[1] = (__bf16)sc[mi][ni][1];
        pk[2] = (__bf16)sc[mi][ni][2]; pk[3] = (__bf16)sc[mi][ni][3];
        int chunk = ni * 2 + (g >> 1);
        int byte = q * 128 + ((chunk ^ (q & 7)) << 4) + (g & 1) * 8;
        *reinterpret_cast<bf16x4*>(pw + byte) = pk;
      }
    }
    asm volatile("s_waitcnt lgkmcnt(0)" ::: "memory");

    // PV: oacc[q][hd] += P[q][kv] * Vt[hd][kv]
    {
      bf16x8 pf[2][2], vf[4][2];
#pragma unroll
      for (int mi = 0; mi < 2; ++mi)
#pragma unroll
        for (int ks = 0; ks < 2; ++ks) {
          int r = mi * 16 + (lane & 15);
          int c = ks * 4 + g;
          pf[mi][ks] = *reinterpret_cast<const bf16x8*>(
              pw + r * 128 + ((c ^ (lane & 7)) << 4));
        }
#pragma unroll
      for (int ni = 0; ni < 4; ++ni)
#pragma unroll
        for (int ks = 0; ks < 2; ++ks) {
          int r = ni * 16 + (lane & 15);
          int c = ks * 4 + g;
          vf[ni][ks] = *reinterpret_cast<const bf16x8*>(
              (const char*)Vs[cur] + r * 128 + ((c ^ (lane & 7)) << 4));
        }
      __builtin_amdgcn_s_setprio(1);
#pragma unroll
      for (int ks = 0; ks < 2; ++ks)
#pragma unroll
        for (int mi = 0; mi < 2; ++mi)
#pragma unroll
          for (int ni = 0; ni < 4; ++ni)
            oacc[mi][ni] = __builtin_amdgcn_mfma_f32_16x16x32_bf16(
                pf[mi][ks], vf[ni][ks], oacc[mi][ni], 0, 0, 0);
      __builtin_amdgcn_s_setprio(0);
    }
  }

  // epilogue: normalize by l (broadcast per oacc row) and store
  const int b = bh >> 4, h = bh & 15;
#pragma unroll
  for (int mi = 0; mi < 2; ++mi)
#pragma unroll
    for (int r = 0; r < 4; ++r) {
      float lr = __shfl(lrow[mi], (g << 2) | r);
      float inv = __builtin_amdgcn_rcpf(lr);
      int qr = qw + mi * 16 + g * 4 + r;
#pragma unroll
      for (int ni = 0; ni < 4; ++ni) {
        int hd = ni * 16 + (lane & 15);
        AO[((int64_t)(b * S_ + qr)) * D_ + h * HD_ + hd] = f2bf(oacc[mi][ni][r] * inv);
      }
    }
}

extern "C" void kernel_launch(void* const* d_in, const int* in_sizes, int n_in,
                              void* d_out, int out_size, void* d_ws, size_t ws_size,
                              hipStream_t stream) {
  const float* x  = (const float*)d_in[0];
  const float* wq = (const float*)d_in[1];
  const float* bq = (const float*)d_in[2];
  const float* wk = (const float*)d_in[3];
  const float* bk = (const float*)d_in[4];
  const float* wv = (const float*)d_in[5];
  const float* bv = (const float*)d_in[6];
  const float* wo = (const float*)d_in[7];
  const float* bo = (const float*)d_in[8];
  char* ws = (char*)d_ws;
  u16* xb  = (u16*)ws;
  u16* wqb = (u16*)(ws + (16ll << 20));
  u16* wkb = (u16*)(ws + (18ll << 20));
  u16* wvb = (u16*)(ws + (20ll << 20));
  u16* wob = (u16*)(ws + (22ll << 20));
  u16* q   = (u16*)(ws + (24ll << 20));
  u16* k   = (u16*)(ws + (40ll << 20));
  u16* vt  = (u16*)(ws + (56ll << 20));
  u16* ao  = xb;

  convert_kernel<<<12288, 256, 0, stream>>>(x, wq, wk, wv, wo, xb, wqb, wkb, wvb, wob);
  dim3 gg(D_ / 128, M_ / 128);
  gemm_kernel<3><<<gg, 256, 0, stream>>>(xb, wqb, bq, q);   // Q, pre-scaled
  gemm_kernel<0><<<gg, 256, 0, stream>>>(xb, wkb, bk, k);
  gemm_kernel<1><<<gg, 256, 0, stream>>>(xb, wvb, bv, vt);  // V^T
  attn_kernel<<<dim3(S_ / 128, B_ * H_), 256, 0, stream>>>(q, k, vt, ao);
  gemm_kernel<2><<<gg, 256, 0, stream>>>(ao, wob, bo, d_out);
}